// Round 1
// baseline (256.128 us; speedup 1.0000x reference)
//
#include <hip/hip_runtime.h>
#include <hip/hip_bf16.h>
#include <stdint.h>
#include <math.h>

#define B_DIM 32
#define T_DIM 1024
#define C_DIM 768
#define NTILE 8                 // T_DIM / 128
#define NTRI  36                // NTILE*(NTILE+1)/2
#define KITER (C_DIM / 32)      // 24
#define NBUF  4                 // K-slice ring buffer depth (prefetch depth 3)

typedef float f32x4 __attribute__((ext_vector_type(4)));

typedef __attribute__((address_space(1))) void gvoid_t;
typedef __attribute__((address_space(3))) void lvoid_t;

// One wave per row: compute 1/||x||_2 and store normalized row as fp8 e4m3.
// Row layout: 768 fp8 bytes = 192 dwords; lane L owns dword L, L+64, L+128
// (elements 4L..4L+3 etc.) -> coalesced dword stores.
__global__ __launch_bounds__(256) void normalize_rows_fp8(const float* __restrict__ x,
                                                          uint32_t* __restrict__ m) {
    const int row  = blockIdx.x * 4 + (threadIdx.x >> 6);
    const int lane = threadIdx.x & 63;
    const float4* xr = (const float4*)(x + (size_t)row * C_DIM);
    float4 v0 = xr[lane];
    float4 v1 = xr[lane + 64];
    float4 v2 = xr[lane + 128];
    float ss = v0.x*v0.x + v0.y*v0.y + v0.z*v0.z + v0.w*v0.w
             + v1.x*v1.x + v1.y*v1.y + v1.z*v1.z + v1.w*v1.w
             + v2.x*v2.x + v2.y*v2.y + v2.z*v2.z + v2.w*v2.w;
    #pragma unroll
    for (int off = 32; off > 0; off >>= 1)
        ss += __shfl_xor(ss, off, 64);
    const float rs = rsqrtf(ss);
    uint32_t* mr = m + (size_t)row * (C_DIM / 4);
    int p;
    p = __builtin_amdgcn_cvt_pk_fp8_f32(v0.x * rs, v0.y * rs, 0, false);
    p = __builtin_amdgcn_cvt_pk_fp8_f32(v0.z * rs, v0.w * rs, p, true);
    mr[lane] = (uint32_t)p;
    p = __builtin_amdgcn_cvt_pk_fp8_f32(v1.x * rs, v1.y * rs, 0, false);
    p = __builtin_amdgcn_cvt_pk_fp8_f32(v1.z * rs, v1.w * rs, p, true);
    mr[lane + 64] = (uint32_t)p;
    p = __builtin_amdgcn_cvt_pk_fp8_f32(v2.x * rs, v2.y * rs, 0, false);
    p = __builtin_amdgcn_cvt_pk_fp8_f32(v2.z * rs, v2.w * rs, p, true);
    mr[lane + 128] = (uint32_t)p;
}

// Batched symmetric NT GEMM on fp8 e4m3: out[b,i,j] = 1 - sum_k M[b,i,k]*M[b,j,k].
// Upper-triangular 128x128 tiles only; off-diagonal mirrored via transposed
// f32x4 stores. Batch-fastest flat grid pins each batch's 36 blocks to one XCD.
//
// K-loop: 4-buffer ring, depth-3 prefetch, COUNTED vmcnt (T4). Per iter:
//   s_waitcnt vmcnt(4)   <- drains only stage(it); stages it+1,it+2 stay in
//   s_barrier                flight ACROSS the barrier (never drain to 0)
//   issue stage(it+3)    <- 3 compute phases of latency slack before use
//   ds_read + 16 MFMA
// Buffer (it+3)&3 was last read at iter it-1; all waves consumed those reads
// (MFMA deps force lgkm drain) before passing this barrier -> WAR safe.
//
// LDS swizzle (16B granularity): row r's 16B-half h stored at h ^ ((r>>2)&1).
// global_load_lds writes linearly, so the swizzle is applied to the GLOBAL
// source address (both-sides-or-neither rule); reads XOR the same bit.
// Cuts the ds_read_b64 per-phase bank aliasing 4-way -> 2-way (free).
__global__ __launch_bounds__(256) void gemm_nt_sym_fp8(const uint8_t* __restrict__ M,
                                                       float* __restrict__ out) {
    // Tile [128][32] fp8 = 4 KB per matrix per buffer (32 KB total).
    __shared__ uint8_t As[NBUF][128 * 32];
    __shared__ uint8_t Bs[NBUF][128 * 32];

    const int b   = blockIdx.x & 31;   // batch fastest -> batch pinned to XCD (b&7)
    const int idx = blockIdx.x >> 5;   // triangular tile index, 0..35
    int tj = (int)((sqrtf(8.0f * (float)idx + 1.0f) - 1.0f) * 0.5f);
    if (tj * (tj + 1) / 2 > idx) --tj;
    const int ti = idx - tj * (tj + 1) / 2;

    const int tid  = threadIdx.x;
    const int wave = tid >> 6;
    const int lane = tid & 63;
    const int quad = lane >> 4;
    const int l16  = lane & 15;
    const int wi = wave >> 1;
    const int wj = wave & 1;

    const uint8_t* Mb = M + (size_t)b * T_DIM * C_DIM;

    // Staging: tile = 4 chunks of 1 KB; wave w stages chunk w of A and of B.
    // Chunk rows: w*32 .. w*32+31 (32 B/row, 2 lanes per row).
    // LDS dest = wave-uniform chunk base + lane*16 (HW rule); the content
    // permutation is realized by XOR-ing the global source column.
    const int srow = wave * 32 + (lane >> 1);
    const int scol = ((lane & 1) * 16) ^ ((((srow >> 2) & 1)) << 4);

    const uint8_t* gA = Mb + (size_t)(ti * 128 + srow) * C_DIM + scol;
    const uint8_t* gB = Mb + (size_t)(tj * 128 + srow) * C_DIM + scol;
    const int cbase = wave * 1024;

    // Precomputed swizzled ds_read byte offsets (within a 4 KB buffer).
    // Fragment row r = w*64 + ii*16 + l16; s(r) = (r>>2)&1 = (l16>>2)&1.
    const int sw = ((l16 >> 2) & 1) << 4;
    int offA[4], offB[4];
    #pragma unroll
    for (int ii = 0; ii < 4; ++ii) {
        offA[ii] = (wi * 64 + ii * 16 + l16) * 32 + ((quad * 8) ^ sw);
        offB[ii] = (wj * 64 + ii * 16 + l16) * 32 + ((quad * 8) ^ sw);
    }

    f32x4 acc[4][4];
    #pragma unroll
    for (int i = 0; i < 4; ++i)
        #pragma unroll
        for (int j = 0; j < 4; ++j)
            acc[i][j] = (f32x4){0.f, 0.f, 0.f, 0.f};

    // Prologue: stage K-slices 0,1,2 (in order; vmcnt drains oldest-first).
    #pragma unroll
    for (int pf = 0; pf < 3; ++pf) {
        __builtin_amdgcn_global_load_lds((gvoid_t*)(gA + pf * 32), (lvoid_t*)&As[pf][cbase], 16, 0, 0);
        __builtin_amdgcn_global_load_lds((gvoid_t*)(gB + pf * 32), (lvoid_t*)&Bs[pf][cbase], 16, 0, 0);
    }

    #pragma unroll 4
    for (int it = 0; it < KITER; ++it) {
        const int cur = it & (NBUF - 1);
        // Drain ONLY stage(it) (2 loads/wave); keep later stages in flight.
        if (it < KITER - 2) {
            asm volatile("s_waitcnt vmcnt(4)" ::: "memory");
        } else {
            asm volatile("s_waitcnt vmcnt(0)" ::: "memory");
        }
        __builtin_amdgcn_s_barrier();
        __builtin_amdgcn_sched_barrier(0);

        if (it + 3 < KITER) {
            const int k0 = (it + 3) * 32;          // byte offset along K
            const int nxt = (it + 3) & (NBUF - 1);
            __builtin_amdgcn_global_load_lds((gvoid_t*)(gA + k0), (lvoid_t*)&As[nxt][cbase], 16, 0, 0);
            __builtin_amdgcn_global_load_lds((gvoid_t*)(gB + k0), (lvoid_t*)&Bs[nxt][cbase], 16, 0, 0);
        }

        const uint8_t* a_base = &As[cur][0];
        const uint8_t* b_base = &Bs[cur][0];
        long af[4], bfr[4];
        #pragma unroll
        for (int ii = 0; ii < 4; ++ii) {
            af[ii]  = *(const long*)(a_base + offA[ii]);
            bfr[ii] = *(const long*)(b_base + offB[ii]);
        }
        #pragma unroll
        for (int ii = 0; ii < 4; ++ii)
            #pragma unroll
            for (int jj = 0; jj < 4; ++jj)
                acc[ii][jj] = __builtin_amdgcn_mfma_f32_16x16x32_fp8_fp8(af[ii], bfr[jj], acc[ii][jj], 0, 0, 0);
    }

    // Epilogue. C/D layout: col = lane&15, row = quad*4 + reg. out = 1 - acc.
    float* outb = out + (size_t)b * T_DIM * T_DIM;
    #pragma unroll
    for (int ii = 0; ii < 4; ++ii) {
        const int rowbase = ti * 128 + wi * 64 + ii * 16 + quad * 4;
        #pragma unroll
        for (int jj = 0; jj < 4; ++jj) {
            const int col = tj * 128 + wj * 64 + jj * 16 + l16;
            #pragma unroll
            for (int r = 0; r < 4; ++r)
                outb[(size_t)(rowbase + r) * T_DIM + col] = 1.0f - acc[ii][jj][r];
        }
    }
    if (ti != tj) {
        // Mirror tile: each lane's 4 acc values share one col and 4 consecutive
        // rows -> one aligned f32x4 store; 4 quads of same l16 cover a 64B line.
        #pragma unroll
        for (int ii = 0; ii < 4; ++ii) {
            const int rowbase = ti * 128 + wi * 64 + ii * 16 + quad * 4;
            #pragma unroll
            for (int jj = 0; jj < 4; ++jj) {
                const int col = tj * 128 + wj * 64 + jj * 16 + l16;
                f32x4 v;
                v[0] = 1.0f - acc[ii][jj][0];
                v[1] = 1.0f - acc[ii][jj][1];
                v[2] = 1.0f - acc[ii][jj][2];
                v[3] = 1.0f - acc[ii][jj][3];
                *(f32x4*)(outb + (size_t)col * T_DIM + rowbase) = v;
            }
        }
    }
}

extern "C" void kernel_launch(void* const* d_in, const int* in_sizes, int n_in,
                              void* d_out, int out_size, void* d_ws, size_t ws_size,
                              hipStream_t stream) {
    const float* x = (const float*)d_in[0];
    float* out = (float*)d_out;
    uint32_t* metric = (uint32_t*)d_ws;  // 32768 x 768 fp8 = 24 MiB

    normalize_rows_fp8<<<dim3((B_DIM * T_DIM) / 4), dim3(256), 0, stream>>>(x, metric);
    // 1152 blocks, batch-fastest: all 36 tiles of batch b share XCD (b&7).
    gemm_nt_sym_fp8<<<dim3(NTRI * B_DIM), dim3(256), 0, stream>>>((const uint8_t*)metric, out);
}